// Round 4
// baseline (582.944 us; speedup 1.0000x reference)
//
#include <hip/hip_runtime.h>
#include <hip/hip_bf16.h>
#include <stdint.h>

// Problem constants
#define BB 4
#define TT 2048
#define DD 1024
#define HH 16
#define HDD 64
// derived
#define M1 (BB*TT)      // 8192 rows
#define N1 (3*DD)       // 3072
#define KDIM DD         // 1024

typedef __attribute__((ext_vector_type(8))) short short8;   // 8 bf16 MFMA operand
typedef __attribute__((ext_vector_type(4))) float f32x4;

#if __has_builtin(__builtin_amdgcn_exp2f)
#define EXP2(x) __builtin_amdgcn_exp2f(x)
#else
#define EXP2(x) exp2f(x)
#endif

__device__ __forceinline__ float bf2f(unsigned short u) {
    union { uint32_t u32; float f; } c; c.u32 = ((uint32_t)u) << 16; return c.f;
}
__device__ __forceinline__ unsigned short f2bf(float f) {
    union { float f; uint32_t u32; } c; c.f = f;
    uint32_t u = c.u32;
    return (unsigned short)((u + 0x7FFFu + ((u >> 16) & 1u)) >> 16);  // RNE
}

// ---------------- elementwise fp32 -> bf16 (x), 4 elems/thread ----------------
__global__ __launch_bounds__(256) void cvt_f32_bf16(
    const float* __restrict__ in, unsigned short* __restrict__ out, int n4)
{
    int i = blockIdx.x * 256 + threadIdx.x;
    if (i >= n4) return;
    float4 v = *(const float4*)&in[(size_t)i * 4];
    ushort4 o;
    o.x = f2bf(v.x); o.y = f2bf(v.y); o.z = f2bf(v.z); o.w = f2bf(v.w);
    *(ushort4*)&out[(size_t)i * 4] = o;
}

// ---------------- transpose+convert: in fp32 [R][C] -> out bf16 [C][R] ----------------
__global__ __launch_bounds__(256) void transpose_f32_bf16(
    const float* __restrict__ in, unsigned short* __restrict__ out,
    int R, int C)
{
    __shared__ unsigned short tile[32][33];
    int bx = blockIdx.x;
    int by = blockIdx.y;
    int x = bx*32 + threadIdx.x;
    int y0 = by*32 + threadIdx.y;
    #pragma unroll
    for (int i = 0; i < 32; i += 8)
        tile[threadIdx.y + i][threadIdx.x] = f2bf(in[(size_t)(y0 + i)*C + x]);
    __syncthreads();
    int xo = by*32 + threadIdx.x;
    int yo = bx*32 + threadIdx.y;
    #pragma unroll
    for (int i = 0; i < 32; i += 8)
        out[(size_t)(yo + i)*R + xo] = tile[threadIdx.x][threadIdx.y + i];
}

// ---------------- MFMA bf16 GEMM ----------------
// MODE 0: bf16 C[M][N]; MODE 1: f32 C[M][N];
// MODE 2: QKV-split — n<2048 -> bf16 QK[M][2048]; n>=2048 -> V transposed to
//         VT[(b*16+h)*64+d][2048]+t (bf16, ushort4-packed: 4 consecutive t per lane).
template <int MODE>
__global__ __launch_bounds__(256) void gemm_bf16_mfma(
    const unsigned short* __restrict__ A, const unsigned short* __restrict__ BT,
    const float* __restrict__ bias, void* __restrict__ Cout, void* __restrict__ Cout2,
    int M, int N, int K)
{
    __shared__ unsigned short As[128*32];
    __shared__ unsigned short Bs[128*32];
    const int tid  = threadIdx.x;
    const int lane = tid & 63;
    const int wave = tid >> 6;
    const int wm = wave >> 1, wn = wave & 1;
    const int quad = lane >> 4, l16 = lane & 15;
    const int m0 = blockIdx.y * 128, n0 = blockIdx.x * 128;

    f32x4 acc[4][4] = {};

    const int nk = K >> 5;
    for (int kt = 0; kt < nk; ++kt) {
        const int k0 = kt << 5;
        __syncthreads();
        #pragma unroll
        for (int h = 0; h < 2; ++h) {
            int c = tid + h*256;
            int row = c >> 2, seg = c & 3;
            uint4 va = *(const uint4*)&A[(size_t)(m0 + row)*K + k0 + seg*8];
            *(uint4*)&As[row*32 + seg*8] = va;
            uint4 vb = *(const uint4*)&BT[(size_t)(n0 + row)*K + k0 + seg*8];
            *(uint4*)&Bs[row*32 + seg*8] = vb;
        }
        __syncthreads();
        short8 af[4], bf[4];
        #pragma unroll
        for (int mi = 0; mi < 4; ++mi)
            af[mi] = *(short8*)&As[(wm*64 + mi*16 + l16)*32 + quad*8];
        #pragma unroll
        for (int ni = 0; ni < 4; ++ni)
            bf[ni] = *(short8*)&Bs[(wn*64 + ni*16 + l16)*32 + quad*8];
        #pragma unroll
        for (int mi = 0; mi < 4; ++mi)
            #pragma unroll
            for (int ni = 0; ni < 4; ++ni)
                acc[mi][ni] = __builtin_amdgcn_mfma_f32_16x16x32_bf16(
                    af[mi], bf[ni], acc[mi][ni], 0, 0, 0);
    }

    if (MODE == 2 && n0 >= 2048) {
        // V third: write transposed VT[(b*16+h)*64+d][t]
        #pragma unroll
        for (int ni = 0; ni < 4; ++ni) {
            int nv = n0 + wn*64 + ni*16 + l16 - 2048;   // 0..1023
            float bv = bias[nv + 2048];
            int hv = nv >> 6, dv = nv & 63;
            #pragma unroll
            for (int mi = 0; mi < 4; ++mi) {
                int m = m0 + wm*64 + mi*16 + quad*4;
                int bb = m >> 11, t = m & 2047;
                ushort4 pk;
                pk.x = f2bf(acc[mi][ni][0] + bv);
                pk.y = f2bf(acc[mi][ni][1] + bv);
                pk.z = f2bf(acc[mi][ni][2] + bv);
                pk.w = f2bf(acc[mi][ni][3] + bv);
                *(ushort4*)&((unsigned short*)Cout2)[((size_t)((bb*16 + hv)*64 + dv))*2048 + t] = pk;
            }
        }
        return;
    }

    const int cstride = (MODE == 2) ? 2048 : N;
    #pragma unroll
    for (int ni = 0; ni < 4; ++ni) {
        int n = n0 + wn*64 + ni*16 + l16;
        float bv = bias[n];
        #pragma unroll
        for (int mi = 0; mi < 4; ++mi) {
            #pragma unroll
            for (int r = 0; r < 4; ++r) {
                int m = m0 + wm*64 + mi*16 + quad*4 + r;
                float val = acc[mi][ni][r] + bv;
                if (MODE == 1)
                    ((float*)Cout)[(size_t)m*cstride + n] = val;
                else
                    ((unsigned short*)Cout)[(size_t)m*cstride + n] = f2bf(val);
            }
        }
    }
}

// ---------------- MFMA flash attention, round 4 ----------------
// grid (16, 64), 256 thr = 4 waves; Q-tile 128 (wave: 32 rows), K-stage 128
// processed as two 64-halves. LDS: QsPs (P aliases Q, stride 68), Ks (stride 68),
// Vt [d][t] stride 136 staged from global VT (pre-transposed by GEMM1) -> all
// uint4 staging, no scalar transpose. 52.2 KB -> 3 blocks/CU.
#define QSTR 68
#define VSTR 136
__global__ __launch_bounds__(256, 3) void attn_mfma(
    const unsigned short* __restrict__ QK, const unsigned short* __restrict__ VT,
    unsigned short* __restrict__ Y)
{
    __shared__ __align__(16) unsigned short QsPs[128*QSTR];
    __shared__ __align__(16) unsigned short Ks[128*QSTR];
    __shared__ __align__(16) unsigned short Vs[64*VSTR];

    const int tid  = threadIdx.x;
    const int lane = tid & 63, wave = tid >> 6;
    const int quad = lane >> 4, l16 = lane & 15;
    const int qt = (gridDim.x - 1) - blockIdx.x;   // big causal blocks first
    const int bh = blockIdx.y;
    const int b = bh >> 4, h = bh & 15;
    const int q0 = qt * 128;
    const int q0w = q0 + wave*32;
    const size_t qkbase = (size_t)(b*TT) * 2048;
    const size_t vbase  = (size_t)(bh*64) * 2048;
    const int qcol = h*64, kcol = 1024 + h*64;
    const float C2 = 0.18033688011112042f;   // (1/sqrt(64)) * log2(e)

    // ---- stage Q: 128 rows x 8 uint4 chunks
    #pragma unroll
    for (int hh = 0; hh < 4; ++hh) {
        int c = tid + hh*256;
        int row = c >> 3, dc = c & 7;
        *(uint4*)&QsPs[row*QSTR + dc*8] =
            *(const uint4*)&QK[qkbase + (size_t)(q0+row)*2048 + qcol + dc*8];
    }
    __syncthreads();

    // Q fragments in registers for the whole loop (then QsPs becomes the P buffer;
    // each wave's P rows == its own Q rows, so no cross-wave hazard)
    short8 aq[2][2];
    #pragma unroll
    for (int mt = 0; mt < 2; ++mt)
        #pragma unroll
        for (int kk = 0; kk < 2; ++kk)
            aq[mt][kk] = *(short8*)&QsPs[(wave*32 + mt*16 + l16)*QSTR + kk*32 + quad*8];

    f32x4 o[2][4] = {};
    float mold[2][4], lsum[2][4];
    #pragma unroll
    for (int mt = 0; mt < 2; ++mt)
        #pragma unroll
        for (int r = 0; r < 4; ++r) { mold[mt][r] = -3.0e38f; lsum[mt][r] = 0.0f; }

    const int nkt = qt + 1;

    // register-prefetch K/V tile 0 (4 uint4 each)
    uint4 kr[4], vr[4];
    #pragma unroll
    for (int hh = 0; hh < 4; ++hh) {
        int c = tid + hh*256;
        int krow = c >> 3, dc = c & 7;
        kr[hh] = *(const uint4*)&QK[qkbase + (size_t)krow*2048 + kcol + dc*8];
        int d = c >> 4, tc = c & 15;
        vr[hh] = *(const uint4*)&VT[vbase + (size_t)d*2048 + tc*8];
    }

    for (int kt = 0; kt < nkt; ++kt) {
        const int k0 = kt * 128;
        __syncthreads();   // prior iteration's Ks/Vs reads complete
        #pragma unroll
        for (int hh = 0; hh < 4; ++hh) {
            int c = tid + hh*256;
            int krow = c >> 3, dc = c & 7;
            *(uint4*)&Ks[krow*QSTR + dc*8] = kr[hh];
            int d = c >> 4, tc = c & 15;
            *(uint4*)&Vs[d*VSTR + tc*8] = vr[hh];
        }
        // prefetch next tile (clamped redundant reload on last iter)
        {
            const int knx = (kt+1 < nkt ? kt+1 : kt) * 128;
            #pragma unroll
            for (int hh = 0; hh < 4; ++hh) {
                int c = tid + hh*256;
                int krow = c >> 3, dc = c & 7;
                kr[hh] = *(const uint4*)&QK[qkbase + (size_t)(knx+krow)*2048 + kcol + dc*8];
                int d = c >> 4, tc = c & 15;
                vr[hh] = *(const uint4*)&VT[vbase + (size_t)d*2048 + knx + tc*8];
            }
        }
        __syncthreads();   // staging visible

        #pragma unroll
        for (int kh = 0; kh < 2; ++kh) {
            const int k0h = k0 + kh*64;
            if (k0h > q0w + 31) continue;   // wave-uniform: half fully above diagonal

            // ---- S = Q K^T  (per-nt causal skip)
            f32x4 s[2][4];
            #pragma unroll
            for (int nt = 0; nt < 4; ++nt) {
                if (k0h + nt*16 <= q0w + 31) {
                    f32x4 z = {};
                    s[0][nt] = z; s[1][nt] = z;
                    #pragma unroll
                    for (int kk = 0; kk < 2; ++kk) {
                        short8 bk = *(short8*)&Ks[(kh*64 + nt*16 + l16)*QSTR + kk*32 + quad*8];
                        s[0][nt] = __builtin_amdgcn_mfma_f32_16x16x32_bf16(aq[0][kk], bk, s[0][nt], 0, 0, 0);
                        s[1][nt] = __builtin_amdgcn_mfma_f32_16x16x32_bf16(aq[1][kk], bk, s[1][nt], 0, 0, 0);
                    }
                } else {
                    #pragma unroll
                    for (int r = 0; r < 4; ++r) { s[0][nt][r] = -3.0e38f; s[1][nt][r] = -3.0e38f; }
                }
            }

            // ---- element causal mask (straddling halves only)
            if (k0h + 63 > q0w) {
                #pragma unroll
                for (int mt = 0; mt < 2; ++mt)
                    #pragma unroll
                    for (int nt = 0; nt < 4; ++nt)
                        #pragma unroll
                        for (int r = 0; r < 4; ++r) {
                            int kg = k0h + nt*16 + l16;
                            int qg = q0w + mt*16 + quad*4 + r;
                            if (kg > qg) s[mt][nt][r] = -3.0e38f;
                        }
            }

            // ---- online softmax (exp2 domain)
            float m2n[2][4], al[2][4];
            #pragma unroll
            for (int mt = 0; mt < 2; ++mt)
                #pragma unroll
                for (int r = 0; r < 4; ++r) {
                    float rm = fmaxf(fmaxf(s[mt][0][r], s[mt][1][r]),
                                     fmaxf(s[mt][2][r], s[mt][3][r]));
                    rm = fmaxf(rm, __shfl_xor(rm, 1, 16));
                    rm = fmaxf(rm, __shfl_xor(rm, 2, 16));
                    rm = fmaxf(rm, __shfl_xor(rm, 4, 16));
                    rm = fmaxf(rm, __shfl_xor(rm, 8, 16));
                    float m2 = fmaxf(mold[mt][r], rm * C2);
                    al[mt][r]  = EXP2(mold[mt][r] - m2);
                    m2n[mt][r] = m2;
                }
            float rs[2][4] = {};
            #pragma unroll
            for (int mt = 0; mt < 2; ++mt)
                #pragma unroll
                for (int nt = 0; nt < 4; ++nt)
                    #pragma unroll
                    for (int r = 0; r < 4; ++r) {
                        float p = EXP2(fmaf(s[mt][nt][r], C2, -m2n[mt][r]));
                        s[mt][nt][r] = p;
                        rs[mt][r] += p;
                    }
            #pragma unroll
            for (int mt = 0; mt < 2; ++mt)
                #pragma unroll
                for (int r = 0; r < 4; ++r) {
                    float t = rs[mt][r];
                    t += __shfl_xor(t, 1, 16);
                    t += __shfl_xor(t, 2, 16);
                    t += __shfl_xor(t, 4, 16);
                    t += __shfl_xor(t, 8, 16);
                    lsum[mt][r] = lsum[mt][r]*al[mt][r] + t;
                    mold[mt][r] = m2n[mt][r];
                }

            // ---- P -> LDS (bf16, own rows; stride-68 => 2-way banks, free)
            #pragma unroll
            for (int mt = 0; mt < 2; ++mt)
                #pragma unroll
                for (int nt = 0; nt < 4; ++nt)
                    #pragma unroll
                    for (int r = 0; r < 4; ++r) {
                        union { float f; uint32_t u; } c; c.f = s[mt][nt][r];
                        QsPs[(wave*32 + mt*16 + quad*4 + r)*QSTR + nt*16 + l16] =
                            (unsigned short)((c.u + 0x8000u) >> 16);
                    }

            // ---- O = O*alpha + P V
            #pragma unroll
            for (int mt = 0; mt < 2; ++mt)
                #pragma unroll
                for (int dt = 0; dt < 4; ++dt)
                    #pragma unroll
                    for (int r = 0; r < 4; ++r)
                        o[mt][dt][r] *= al[mt][r];
            #pragma unroll
            for (int kk = 0; kk < 2; ++kk) {
                short8 ap0 = *(short8*)&QsPs[(wave*32 +      l16)*QSTR + kk*32 + quad*8];
                short8 ap1 = *(short8*)&QsPs[(wave*32 + 16 + l16)*QSTR + kk*32 + quad*8];
                #pragma unroll
                for (int dt = 0; dt < 4; ++dt) {
                    short8 bv = *(short8*)&Vs[(dt*16 + l16)*VSTR + kh*64 + kk*32 + quad*8];
                    o[0][dt] = __builtin_amdgcn_mfma_f32_16x16x32_bf16(ap0, bv, o[0][dt], 0, 0, 0);
                    o[1][dt] = __builtin_amdgcn_mfma_f32_16x16x32_bf16(ap1, bv, o[1][dt], 0, 0, 0);
                }
            }
        }
    }

    // ---- normalize + store (bf16 intermediate Y)
    #pragma unroll
    for (int mt = 0; mt < 2; ++mt)
        #pragma unroll
        for (int r = 0; r < 4; ++r) {
            float inv = 1.0f / lsum[mt][r];
            int t = q0w + mt*16 + quad*4 + r;
            #pragma unroll
            for (int dt = 0; dt < 4; ++dt)
                Y[((size_t)(b*TT + t))*DD + h*64 + dt*16 + l16] = f2bf(o[mt][dt][r] * inv);
        }
}

extern "C" void kernel_launch(void* const* d_in, const int* in_sizes, int n_in,
                              void* d_out, int out_size, void* d_ws, size_t ws_size,
                              hipStream_t stream)
{
    const float* x    = (const float*)d_in[0];   // [4,2048,1024] fp32
    // d_in[1] = causal_mask (int32) — causality implemented analytically, unused
    const float* wqkv = (const float*)d_in[2];   // [1024][3072] fp32
    const float* bqkv = (const float*)d_in[3];   // [3072] fp32
    const float* wout = (const float*)d_in[4];   // [1024][1024] fp32
    const float* bout = (const float*)d_in[5];   // [1024] fp32
    float* out = (float*)d_out;                  // [4,2048,1024] fp32

    char* ws = (char*)d_ws;
    unsigned short* Xb    = (unsigned short*)ws;                    // 16 MB
    unsigned short* WqkvT = (unsigned short*)(ws + 16777216);       // 6 MB
    unsigned short* WoutT = (unsigned short*)(ws + 23068672);       // 2 MB
    unsigned short* QK    = (unsigned short*)(ws + 25165824);       // 32 MB [M][2048]
    unsigned short* VTb   = (unsigned short*)(ws + 58720256);       // 16 MB [bh*64+d][2048]
    unsigned short* Ybuf  = (unsigned short*)(ws + 75497472);       // 16 MB

    cvt_f32_bf16<<<(M1*KDIM/4 + 255)/256, 256, 0, stream>>>(x, Xb, M1*KDIM/4);
    transpose_f32_bf16<<<dim3(N1/32, KDIM/32), dim3(32, 8), 0, stream>>>(wqkv, WqkvT, KDIM, N1);
    transpose_f32_bf16<<<dim3(DD/32, KDIM/32), dim3(32, 8), 0, stream>>>(wout, WoutT, KDIM, DD);
    gemm_bf16_mfma<2><<<dim3(N1/128, M1/128), 256, 0, stream>>>(Xb, WqkvT, bqkv, QK, VTb, M1, N1, KDIM);
    attn_mfma<<<dim3(TT/128, BB*HH), 256, 0, stream>>>(QK, VTb, Ybuf);
    gemm_bf16_mfma<1><<<dim3(DD/128, M1/128), 256, 0, stream>>>(Ybuf, WoutT, bout, out, nullptr, M1, DD, KDIM);
}

// Round 5
// 572.017 us; speedup vs baseline: 1.0191x; 1.0191x over previous
//
#include <hip/hip_runtime.h>
#include <hip/hip_bf16.h>
#include <stdint.h>

// Problem constants
#define BB 4
#define TT 2048
#define DD 1024
#define HH 16
#define HDD 64
// derived
#define M1 (BB*TT)      // 8192 rows
#define N1 (3*DD)       // 3072
#define KDIM DD         // 1024

typedef __attribute__((ext_vector_type(8))) short short8;   // 8 bf16 MFMA operand
typedef __attribute__((ext_vector_type(4))) float f32x4;

#if __has_builtin(__builtin_amdgcn_exp2f)
#define EXP2(x) __builtin_amdgcn_exp2f(x)
#else
#define EXP2(x) exp2f(x)
#endif

__device__ __forceinline__ float bf2f(unsigned short u) {
    union { uint32_t u32; float f; } c; c.u32 = ((uint32_t)u) << 16; return c.f;
}
__device__ __forceinline__ unsigned short f2bf(float f) {
    union { float f; uint32_t u32; } c; c.f = f;
    uint32_t u = c.u32;
    return (unsigned short)((u + 0x7FFFu + ((u >> 16) & 1u)) >> 16);  // RNE
}

// ---------------- elementwise fp32 -> bf16 (x), 4 elems/thread ----------------
__global__ __launch_bounds__(256) void cvt_f32_bf16(
    const float* __restrict__ in, unsigned short* __restrict__ out, int n4)
{
    int i = blockIdx.x * 256 + threadIdx.x;
    if (i >= n4) return;
    float4 v = *(const float4*)&in[(size_t)i * 4];
    ushort4 o;
    o.x = f2bf(v.x); o.y = f2bf(v.y); o.z = f2bf(v.z); o.w = f2bf(v.w);
    *(ushort4*)&out[(size_t)i * 4] = o;
}

// ---------------- transpose+convert: in fp32 [R][C] -> out bf16 [C][R] ----------------
__global__ __launch_bounds__(256) void transpose_f32_bf16(
    const float* __restrict__ in, unsigned short* __restrict__ out,
    int R, int C)
{
    __shared__ unsigned short tile[32][33];
    int bx = blockIdx.x;
    int by = blockIdx.y;
    int x = bx*32 + threadIdx.x;
    int y0 = by*32 + threadIdx.y;
    #pragma unroll
    for (int i = 0; i < 32; i += 8)
        tile[threadIdx.y + i][threadIdx.x] = f2bf(in[(size_t)(y0 + i)*C + x]);
    __syncthreads();
    int xo = by*32 + threadIdx.x;
    int yo = bx*32 + threadIdx.y;
    #pragma unroll
    for (int i = 0; i < 32; i += 8)
        out[(size_t)(yo + i)*R + xo] = tile[threadIdx.x][threadIdx.y + i];
}

// ---------------- MFMA bf16 GEMM ----------------
// MODE 1: f32 C[M][N]
// MODE 2: QKV-split — n<2048 -> bf16 QK[M][2048]; n>=2048 -> V transposed via
//         LDS to VT[((b*16+h)*64+d)][2048]+t with fully-coalesced 16B stores.
#define TSTR 132
template <int MODE>
__global__ __launch_bounds__(256) void gemm_bf16_mfma(
    const unsigned short* __restrict__ A, const unsigned short* __restrict__ BT,
    const float* __restrict__ bias, void* __restrict__ Cout, void* __restrict__ Cout2,
    int M, int N, int K)
{
    constexpr int SHSZ = (MODE == 2) ? 128*TSTR : 128*64;
    __shared__ __align__(16) unsigned short Sh[SHSZ];
    unsigned short* As = Sh;            // 128*32 shorts
    unsigned short* Bs = Sh + 128*32;   // 128*32 shorts
    const int tid  = threadIdx.x;
    const int lane = tid & 63;
    const int wave = tid >> 6;
    const int wm = wave >> 1, wn = wave & 1;
    const int quad = lane >> 4, l16 = lane & 15;
    const int m0 = blockIdx.y * 128, n0 = blockIdx.x * 128;

    f32x4 acc[4][4] = {};

    const int nk = K >> 5;
    for (int kt = 0; kt < nk; ++kt) {
        const int k0 = kt << 5;
        __syncthreads();
        #pragma unroll
        for (int h = 0; h < 2; ++h) {
            int c = tid + h*256;
            int row = c >> 2, seg = c & 3;
            uint4 va = *(const uint4*)&A[(size_t)(m0 + row)*K + k0 + seg*8];
            *(uint4*)&As[row*32 + seg*8] = va;
            uint4 vb = *(const uint4*)&BT[(size_t)(n0 + row)*K + k0 + seg*8];
            *(uint4*)&Bs[row*32 + seg*8] = vb;
        }
        __syncthreads();
        short8 af[4], bf[4];
        #pragma unroll
        for (int mi = 0; mi < 4; ++mi)
            af[mi] = *(short8*)&As[(wm*64 + mi*16 + l16)*32 + quad*8];
        #pragma unroll
        for (int ni = 0; ni < 4; ++ni)
            bf[ni] = *(short8*)&Bs[(wn*64 + ni*16 + l16)*32 + quad*8];
        #pragma unroll
        for (int mi = 0; mi < 4; ++mi)
            #pragma unroll
            for (int ni = 0; ni < 4; ++ni)
                acc[mi][ni] = __builtin_amdgcn_mfma_f32_16x16x32_bf16(
                    af[mi], bf[ni], acc[mi][ni], 0, 0, 0);
    }

    if (MODE == 2 && n0 >= 2048) {
        // V third: transpose through LDS, then coalesced 16B stores to VT[d-row][t]
        __syncthreads();   // all As/Bs reads done before aliasing Sh
        #pragma unroll
        for (int ni = 0; ni < 4; ++ni) {
            int nl = wn*64 + ni*16 + l16;        // local n 0..127
            float bv = bias[n0 + nl];
            #pragma unroll
            for (int mi = 0; mi < 4; ++mi) {
                ushort4 pk;
                pk.x = f2bf(acc[mi][ni][0] + bv);
                pk.y = f2bf(acc[mi][ni][1] + bv);
                pk.z = f2bf(acc[mi][ni][2] + bv);
                pk.w = f2bf(acc[mi][ni][3] + bv);
                *(ushort4*)&Sh[nl*TSTR + wm*64 + mi*16 + quad*4] = pk;
            }
        }
        __syncthreads();
        const int bb = m0 >> 11, t0 = m0 & 2047;
        #pragma unroll
        for (int p = 0; p < 8; ++p) {
            int c = tid + p*256;
            int row = c >> 4, ch = c & 15;       // row: local n, ch: 8-short chunk of m
            int nv = n0 + row - 2048;            // 0..1023
            int hv = nv >> 6, dv = nv & 63;
            *(uint4*)&((unsigned short*)Cout2)[((size_t)((bb*16 + hv)*64 + dv))*2048 + t0 + ch*8] =
                *(uint4*)&Sh[row*TSTR + ch*8];
        }
        return;
    }

    const int cstride = (MODE == 2) ? 2048 : N;
    #pragma unroll
    for (int ni = 0; ni < 4; ++ni) {
        int n = n0 + wn*64 + ni*16 + l16;
        float bv = bias[n];
        #pragma unroll
        for (int mi = 0; mi < 4; ++mi) {
            #pragma unroll
            for (int r = 0; r < 4; ++r) {
                int m = m0 + wm*64 + mi*16 + quad*4 + r;
                float val = acc[mi][ni][r] + bv;
                if (MODE == 1)
                    ((float*)Cout)[(size_t)m*cstride + n] = val;
                else
                    ((unsigned short*)Cout)[(size_t)m*cstride + n] = f2bf(val);
            }
        }
    }
}

// ---------------- MFMA flash attention, round 5: barrier-free per-wave ----------------
// grid (64, 64): x = 32-row q-tile (reversed), y = bh. Block = 64 threads = 1 wave.
// No __syncthreads anywhere. K/V MFMA fragments loaded DIRECTLY from global
// (same lane pattern as the verified LDS reads, stride 2048) — L1/L2 serve
// repeats across co-resident waves. LDS holds only this wave's P (32x72, 4.6 KB).
// V-frag loads issued before softmax so their latency hides under the exp chain.
#define PST 72
__global__ __launch_bounds__(64, 4) void attn_mfma(
    const unsigned short* __restrict__ QK, const unsigned short* __restrict__ VT,
    unsigned short* __restrict__ Y)
{
    __shared__ __align__(16) unsigned short Ps[32*PST];

    const int lane = threadIdx.x;
    const int quad = lane >> 4, l16 = lane & 15;
    const int qw = (gridDim.x - 1) - blockIdx.x;   // long causal rows dispatch first
    const int bh = blockIdx.y;
    const int b = bh >> 4, h = bh & 15;
    const int q0w = qw * 32;
    const size_t qkbase = (size_t)(b*TT) * 2048;
    const size_t vbase  = (size_t)(bh*64) * 2048;
    const int qcol = h*64, kcol = 1024 + h*64;
    const float C2 = 0.18033688011112042f;   // (1/sqrt(64)) * log2(e)

    // Q fragments straight from global (held for the whole loop)
    short8 aq[2][2];
    #pragma unroll
    for (int mt = 0; mt < 2; ++mt)
        #pragma unroll
        for (int kk = 0; kk < 2; ++kk)
            aq[mt][kk] = *(const short8*)&QK[qkbase + (size_t)(q0w + mt*16 + l16)*2048
                                            + qcol + kk*32 + quad*8];

    f32x4 o[2][4] = {};
    float mold[2][4], lsum[2][4];
    #pragma unroll
    for (int mt = 0; mt < 2; ++mt)
        #pragma unroll
        for (int r = 0; r < 4; ++r) { mold[mt][r] = -3.0e38f; lsum[mt][r] = 0.0f; }

    const int nkt = ((q0w + 31) >> 6) + 1;

    for (int kt = 0; kt < nkt; ++kt) {
        const int k0 = kt * 64;

        // ---- S = Q K^T, K frags from global (per-nt causal skip, wave-uniform)
        f32x4 s[2][4];
        #pragma unroll
        for (int nt = 0; nt < 4; ++nt) {
            if (k0 + nt*16 <= q0w + 31) {
                f32x4 z = {};
                s[0][nt] = z; s[1][nt] = z;
                #pragma unroll
                for (int kk = 0; kk < 2; ++kk) {
                    short8 bk = *(const short8*)&QK[qkbase + (size_t)(k0 + nt*16 + l16)*2048
                                                    + kcol + kk*32 + quad*8];
                    s[0][nt] = __builtin_amdgcn_mfma_f32_16x16x32_bf16(aq[0][kk], bk, s[0][nt], 0, 0, 0);
                    s[1][nt] = __builtin_amdgcn_mfma_f32_16x16x32_bf16(aq[1][kk], bk, s[1][nt], 0, 0, 0);
                }
            } else {
                #pragma unroll
                for (int r = 0; r < 4; ++r) { s[0][nt][r] = -3.0e38f; s[1][nt][r] = -3.0e38f; }
            }
        }

        // ---- issue V-frag loads now; latency hides under softmax (independent)
        short8 bv[2][4];
        #pragma unroll
        for (int kk = 0; kk < 2; ++kk)
            #pragma unroll
            for (int dt = 0; dt < 4; ++dt)
                bv[kk][dt] = *(const short8*)&VT[vbase + (size_t)(dt*16 + l16)*2048
                                                 + k0 + kk*32 + quad*8];

        // ---- element causal mask (straddling tiles only)
        if (k0 + 63 > q0w) {
            #pragma unroll
            for (int mt = 0; mt < 2; ++mt)
                #pragma unroll
                for (int nt = 0; nt < 4; ++nt)
                    #pragma unroll
                    for (int r = 0; r < 4; ++r) {
                        int kg = k0 + nt*16 + l16;
                        int qg = q0w + mt*16 + quad*4 + r;
                        if (kg > qg) s[mt][nt][r] = -3.0e38f;
                    }
        }

        // ---- online softmax (exp2 domain)
        float m2n[2][4], al[2][4];
        #pragma unroll
        for (int mt = 0; mt < 2; ++mt)
            #pragma unroll
            for (int r = 0; r < 4; ++r) {
                float rm = fmaxf(fmaxf(s[mt][0][r], s[mt][1][r]),
                                 fmaxf(s[mt][2][r], s[mt][3][r]));
                rm = fmaxf(rm, __shfl_xor(rm, 1, 16));
                rm = fmaxf(rm, __shfl_xor(rm, 2, 16));
                rm = fmaxf(rm, __shfl_xor(rm, 4, 16));
                rm = fmaxf(rm, __shfl_xor(rm, 8, 16));
                float m2 = fmaxf(mold[mt][r], rm * C2);
                al[mt][r]  = EXP2(mold[mt][r] - m2);
                m2n[mt][r] = m2;
            }
        float rs[2][4] = {};
        #pragma unroll
        for (int mt = 0; mt < 2; ++mt)
            #pragma unroll
            for (int nt = 0; nt < 4; ++nt)
                #pragma unroll
                for (int r = 0; r < 4; ++r) {
                    float p = EXP2(fmaf(s[mt][nt][r], C2, -m2n[mt][r]));
                    s[mt][nt][r] = p;
                    rs[mt][r] += p;
                }
        #pragma unroll
        for (int mt = 0; mt < 2; ++mt)
            #pragma unroll
            for (int r = 0; r < 4; ++r) {
                float t = rs[mt][r];
                t += __shfl_xor(t, 1, 16);
                t += __shfl_xor(t, 2, 16);
                t += __shfl_xor(t, 4, 16);
                t += __shfl_xor(t, 8, 16);
                lsum[mt][r] = lsum[mt][r]*al[mt][r] + t;
                mold[mt][r] = m2n[mt][r];
            }

        // ---- P -> LDS (this wave's private buffer; same-wave RAW, no barrier)
        #pragma unroll
        for (int mt = 0; mt < 2; ++mt)
            #pragma unroll
            for (int nt = 0; nt < 4; ++nt)
                #pragma unroll
                for (int r = 0; r < 4; ++r) {
                    union { float f; uint32_t u; } c; c.f = s[mt][nt][r];
                    Ps[(mt*16 + quad*4 + r)*PST + nt*16 + l16] =
                        (unsigned short)((c.u + 0x8000u) >> 16);
                }

        // ---- O = O*alpha + P V
        #pragma unroll
        for (int mt = 0; mt < 2; ++mt)
            #pragma unroll
            for (int dt = 0; dt < 4; ++dt)
                #pragma unroll
                for (int r = 0; r < 4; ++r)
                    o[mt][dt][r] *= al[mt][r];
        #pragma unroll
        for (int kk = 0; kk < 2; ++kk) {
            short8 ap0 = *(short8*)&Ps[(     l16)*PST + kk*32 + quad*8];
            short8 ap1 = *(short8*)&Ps[(16 + l16)*PST + kk*32 + quad*8];
            #pragma unroll
            for (int dt = 0; dt < 4; ++dt) {
                o[0][dt] = __builtin_amdgcn_mfma_f32_16x16x32_bf16(ap0, bv[kk][dt], o[0][dt], 0, 0, 0);
                o[1][dt] = __builtin_amdgcn_mfma_f32_16x16x32_bf16(ap1, bv[kk][dt], o[1][dt], 0, 0, 0);
            }
        }
    }

    // ---- normalize + store (bf16 intermediate Y)
    #pragma unroll
    for (int mt = 0; mt < 2; ++mt)
        #pragma unroll
        for (int r = 0; r < 4; ++r) {
            float inv = 1.0f / lsum[mt][r];
            int t = q0w + mt*16 + quad*4 + r;
            #pragma unroll
            for (int dt = 0; dt < 4; ++dt)
                Y[((size_t)(b*TT + t))*DD + h*64 + dt*16 + l16] = f2bf(o[mt][dt][r] * inv);
        }
}

extern "C" void kernel_launch(void* const* d_in, const int* in_sizes, int n_in,
                              void* d_out, int out_size, void* d_ws, size_t ws_size,
                              hipStream_t stream)
{
    const float* x    = (const float*)d_in[0];   // [4,2048,1024] fp32
    // d_in[1] = causal_mask (int32) — causality implemented analytically, unused
    const float* wqkv = (const float*)d_in[2];   // [1024][3072] fp32
    const float* bqkv = (const float*)d_in[3];   // [3072] fp32
    const float* wout = (const float*)d_in[4];   // [1024][1024] fp32
    const float* bout = (const float*)d_in[5];   // [1024] fp32
    float* out = (float*)d_out;                  // [4,2048,1024] fp32

    char* ws = (char*)d_ws;
    unsigned short* Xb    = (unsigned short*)ws;                    // 16 MB
    unsigned short* WqkvT = (unsigned short*)(ws + 16777216);       // 6 MB
    unsigned short* WoutT = (unsigned short*)(ws + 23068672);       // 2 MB
    unsigned short* QK    = (unsigned short*)(ws + 25165824);       // 32 MB [M][2048]
    unsigned short* VTb   = (unsigned short*)(ws + 58720256);       // 16 MB [(bh*64+d)][2048]
    unsigned short* Ybuf  = (unsigned short*)(ws + 75497472);       // 16 MB

    cvt_f32_bf16<<<(M1*KDIM/4 + 255)/256, 256, 0, stream>>>(x, Xb, M1*KDIM/4);
    transpose_f32_bf16<<<dim3(N1/32, KDIM/32), dim3(32, 8), 0, stream>>>(wqkv, WqkvT, KDIM, N1);
    transpose_f32_bf16<<<dim3(DD/32, KDIM/32), dim3(32, 8), 0, stream>>>(wout, WoutT, KDIM, DD);
    gemm_bf16_mfma<2><<<dim3(N1/128, M1/128), 256, 0, stream>>>(Xb, WqkvT, bqkv, QK, VTb, M1, N1, KDIM);
    attn_mfma<<<dim3(TT/32, BB*HH), 64, 0, stream>>>(QK, VTb, Ybuf);
    gemm_bf16_mfma<1><<<dim3(DD/128, M1/128), 256, 0, stream>>>(Ybuf, WoutT, bout, out, nullptr, M1, DD, KDIM);
}

// Round 6
// 454.454 us; speedup vs baseline: 1.2827x; 1.2587x over previous
//
#include <hip/hip_runtime.h>
#include <hip/hip_bf16.h>
#include <stdint.h>

// Problem constants
#define BB 4
#define TT 2048
#define DD 1024
#define HH 16
#define HDD 64
// derived
#define M1 (BB*TT)      // 8192 rows
#define N1 (3*DD)       // 3072
#define KDIM DD         // 1024

typedef __attribute__((ext_vector_type(8))) short short8;   // 8 bf16 MFMA operand
typedef __attribute__((ext_vector_type(4))) float f32x4;

#if __has_builtin(__builtin_amdgcn_exp2f)
#define EXP2(x) __builtin_amdgcn_exp2f(x)
#else
#define EXP2(x) exp2f(x)
#endif

// async global->LDS, 16B per lane (global_load_lds_dwordx4)
#define GLOAD_LDS16(gp, lp) \
    __builtin_amdgcn_global_load_lds( \
        (const __attribute__((address_space(1))) void*)(gp), \
        (__attribute__((address_space(3))) void*)(lp), 16, 0, 0)

__device__ __forceinline__ float bf2f(unsigned short u) {
    union { uint32_t u32; float f; } c; c.u32 = ((uint32_t)u) << 16; return c.f;
}
__device__ __forceinline__ unsigned short f2bf(float f) {
    union { float f; uint32_t u32; } c; c.f = f;
    uint32_t u = c.u32;
    return (unsigned short)((u + 0x7FFFu + ((u >> 16) & 1u)) >> 16);  // RNE
}

// ---------------- elementwise fp32 -> bf16 (x), 4 elems/thread ----------------
__global__ __launch_bounds__(256) void cvt_f32_bf16(
    const float* __restrict__ in, unsigned short* __restrict__ out, int n4)
{
    int i = blockIdx.x * 256 + threadIdx.x;
    if (i >= n4) return;
    float4 v = *(const float4*)&in[(size_t)i * 4];
    ushort4 o;
    o.x = f2bf(v.x); o.y = f2bf(v.y); o.z = f2bf(v.z); o.w = f2bf(v.w);
    *(ushort4*)&out[(size_t)i * 4] = o;
}

// ---------------- transpose+convert: in fp32 [R][C] -> out bf16 [C][R] ----------------
__global__ __launch_bounds__(256) void transpose_f32_bf16(
    const float* __restrict__ in, unsigned short* __restrict__ out,
    int R, int C)
{
    __shared__ unsigned short tile[32][33];
    int bx = blockIdx.x;
    int by = blockIdx.y;
    int x = bx*32 + threadIdx.x;
    int y0 = by*32 + threadIdx.y;
    #pragma unroll
    for (int i = 0; i < 32; i += 8)
        tile[threadIdx.y + i][threadIdx.x] = f2bf(in[(size_t)(y0 + i)*C + x]);
    __syncthreads();
    int xo = by*32 + threadIdx.x;
    int yo = bx*32 + threadIdx.y;
    #pragma unroll
    for (int i = 0; i < 32; i += 8)
        out[(size_t)(yo + i)*R + xo] = tile[threadIdx.x][threadIdx.y + i];
}

// ---------------- MFMA bf16 GEMM ----------------
// MODE 1: f32 C[M][N]
// MODE 2: QKV-split — n<2048 -> bf16 QK[M][2048]; n>=2048 -> V transposed via
//         LDS to VT[((b*16+h)*64+d)][2048]+t with fully-coalesced 16B stores.
// Staging via global_load_lds width=16 (m97 pattern): LDS offset of chunk c is
// exactly c*16 B, wave-uniform base + lane*16 — satisfies the HW constraint.
#define TSTR 132
template <int MODE>
__global__ __launch_bounds__(256) void gemm_bf16_mfma(
    const unsigned short* __restrict__ A, const unsigned short* __restrict__ BT,
    const float* __restrict__ bias, void* __restrict__ Cout, void* __restrict__ Cout2,
    int M, int N, int K)
{
    constexpr int SHSZ = (MODE == 2) ? 128*TSTR : 128*64;
    __shared__ __align__(16) unsigned short Sh[SHSZ];
    unsigned short* As = Sh;            // 128*32 shorts
    unsigned short* Bs = Sh + 128*32;   // 128*32 shorts
    const int tid  = threadIdx.x;
    const int lane = tid & 63;
    const int wave = tid >> 6;
    const int wm = wave >> 1, wn = wave & 1;
    const int quad = lane >> 4, l16 = lane & 15;
    const int m0 = blockIdx.y * 128, n0 = blockIdx.x * 128;

    f32x4 acc[4][4] = {};

    const int nk = K >> 5;
    for (int kt = 0; kt < nk; ++kt) {
        const int k0 = kt << 5;
        __syncthreads();
        #pragma unroll
        for (int h = 0; h < 2; ++h) {
            int c = tid + h*256;
            int row = c >> 2, seg = c & 3;
            GLOAD_LDS16(&A[(size_t)(m0 + row)*K + k0 + seg*8], &As[row*32 + seg*8]);
            GLOAD_LDS16(&BT[(size_t)(n0 + row)*K + k0 + seg*8], &Bs[row*32 + seg*8]);
        }
        __syncthreads();   // compiler drains vmcnt before barrier
        short8 af[4], bf[4];
        #pragma unroll
        for (int mi = 0; mi < 4; ++mi)
            af[mi] = *(short8*)&As[(wm*64 + mi*16 + l16)*32 + quad*8];
        #pragma unroll
        for (int ni = 0; ni < 4; ++ni)
            bf[ni] = *(short8*)&Bs[(wn*64 + ni*16 + l16)*32 + quad*8];
        #pragma unroll
        for (int mi = 0; mi < 4; ++mi)
            #pragma unroll
            for (int ni = 0; ni < 4; ++ni)
                acc[mi][ni] = __builtin_amdgcn_mfma_f32_16x16x32_bf16(
                    af[mi], bf[ni], acc[mi][ni], 0, 0, 0);
    }

    if (MODE == 2 && n0 >= 2048) {
        // V third: transpose through LDS, then coalesced 16B stores to VT[d-row][t]
        __syncthreads();   // all As/Bs reads done before aliasing Sh
        #pragma unroll
        for (int ni = 0; ni < 4; ++ni) {
            int nl = wn*64 + ni*16 + l16;        // local n 0..127
            float bv = bias[n0 + nl];
            #pragma unroll
            for (int mi = 0; mi < 4; ++mi) {
                ushort4 pk;
                pk.x = f2bf(acc[mi][ni][0] + bv);
                pk.y = f2bf(acc[mi][ni][1] + bv);
                pk.z = f2bf(acc[mi][ni][2] + bv);
                pk.w = f2bf(acc[mi][ni][3] + bv);
                *(ushort4*)&Sh[nl*TSTR + wm*64 + mi*16 + quad*4] = pk;
            }
        }
        __syncthreads();
        const int bb = m0 >> 11, t0 = m0 & 2047;
        #pragma unroll
        for (int p = 0; p < 8; ++p) {
            int c = tid + p*256;
            int row = c >> 4, ch = c & 15;       // row: local n, ch: 8-short chunk of m
            int nv = n0 + row - 2048;            // 0..1023
            int hv = nv >> 6, dv = nv & 63;
            *(uint4*)&((unsigned short*)Cout2)[((size_t)((bb*16 + hv)*64 + dv))*2048 + t0 + ch*8] =
                *(uint4*)&Sh[row*TSTR + ch*8];
        }
        return;
    }

    const int cstride = (MODE == 2) ? 2048 : N;
    #pragma unroll
    for (int ni = 0; ni < 4; ++ni) {
        int n = n0 + wn*64 + ni*16 + l16;
        float bv = bias[n];
        #pragma unroll
        for (int mi = 0; mi < 4; ++mi) {
            #pragma unroll
            for (int r = 0; r < 4; ++r) {
                int m = m0 + wm*64 + mi*16 + quad*4 + r;
                float val = acc[mi][ni][r] + bv;
                if (MODE == 1)
                    ((float*)Cout)[(size_t)m*cstride + n] = val;
                else
                    ((unsigned short*)Cout)[(size_t)m*cstride + n] = f2bf(val);
            }
        }
    }
}

// ---------------- MFMA flash attention: barrier-free per-wave ----------------
// grid (64, 64): x = 32-row q-tile (reversed), y = bh. Block = 64 threads = 1 wave.
// No __syncthreads anywhere. K/V MFMA fragments loaded DIRECTLY from global;
// L1/L2 serve repeats across co-resident waves. LDS holds only this wave's P.
// __launch_bounds__(64, 2): unified VGPR+AGPR budget = 512/2 = 256/wave.
// Round-5's (64,4) capped it at 128 -> scratch spills = ~300 MB phantom HBM
// traffic (WRITE_SIZE 169 MB vs 16 MB of real stores). DO NOT raise to 3+
// without re-checking spills.
#define PST 72
__global__ __launch_bounds__(64, 2) void attn_mfma(
    const unsigned short* __restrict__ QK, const unsigned short* __restrict__ VT,
    unsigned short* __restrict__ Y)
{
    __shared__ __align__(16) unsigned short Ps[32*PST];

    const int lane = threadIdx.x;
    const int quad = lane >> 4, l16 = lane & 15;
    const int qw = (gridDim.x - 1) - blockIdx.x;   // long causal rows dispatch first
    const int bh = blockIdx.y;
    const int b = bh >> 4, h = bh & 15;
    const int q0w = qw * 32;
    const size_t qkbase = (size_t)(b*TT) * 2048;
    const size_t vbase  = (size_t)(bh*64) * 2048;
    const int qcol = h*64, kcol = 1024 + h*64;
    const float C2 = 0.18033688011112042f;   // (1/sqrt(64)) * log2(e)

    // Q fragments straight from global (held for the whole loop)
    short8 aq[2][2];
    #pragma unroll
    for (int mt = 0; mt < 2; ++mt)
        #pragma unroll
        for (int kk = 0; kk < 2; ++kk)
            aq[mt][kk] = *(const short8*)&QK[qkbase + (size_t)(q0w + mt*16 + l16)*2048
                                            + qcol + kk*32 + quad*8];

    f32x4 o[2][4] = {};
    float mold[2][4], lsum[2][4];
    #pragma unroll
    for (int mt = 0; mt < 2; ++mt)
        #pragma unroll
        for (int r = 0; r < 4; ++r) { mold[mt][r] = -3.0e38f; lsum[mt][r] = 0.0f; }

    const int nkt = ((q0w + 31) >> 6) + 1;

    for (int kt = 0; kt < nkt; ++kt) {
        const int k0 = kt * 64;

        // ---- S = Q K^T, K frags from global (per-nt causal skip, wave-uniform)
        f32x4 s[2][4];
        #pragma unroll
        for (int nt = 0; nt < 4; ++nt) {
            if (k0 + nt*16 <= q0w + 31) {
                f32x4 z = {};
                s[0][nt] = z; s[1][nt] = z;
                #pragma unroll
                for (int kk = 0; kk < 2; ++kk) {
                    short8 bk = *(const short8*)&QK[qkbase + (size_t)(k0 + nt*16 + l16)*2048
                                                    + kcol + kk*32 + quad*8];
                    s[0][nt] = __builtin_amdgcn_mfma_f32_16x16x32_bf16(aq[0][kk], bk, s[0][nt], 0, 0, 0);
                    s[1][nt] = __builtin_amdgcn_mfma_f32_16x16x32_bf16(aq[1][kk], bk, s[1][nt], 0, 0, 0);
                }
            } else {
                #pragma unroll
                for (int r = 0; r < 4; ++r) { s[0][nt][r] = -3.0e38f; s[1][nt][r] = -3.0e38f; }
            }
        }

        // ---- issue V-frag loads now; latency hides under softmax (independent)
        short8 bv[2][4];
        #pragma unroll
        for (int kk = 0; kk < 2; ++kk)
            #pragma unroll
            for (int dt = 0; dt < 4; ++dt)
                bv[kk][dt] = *(const short8*)&VT[vbase + (size_t)(dt*16 + l16)*2048
                                                 + k0 + kk*32 + quad*8];

        // ---- element causal mask (straddling tiles only)
        if (k0 + 63 > q0w) {
            #pragma unroll
            for (int mt = 0; mt < 2; ++mt)
                #pragma unroll
                for (int nt = 0; nt < 4; ++nt)
                    #pragma unroll
                    for (int r = 0; r < 4; ++r) {
                        int kg = k0 + nt*16 + l16;
                        int qg = q0w + mt*16 + quad*4 + r;
                        if (kg > qg) s[mt][nt][r] = -3.0e38f;
                    }
        }

        // ---- online softmax (exp2 domain)
        float m2n[2][4], al[2][4];
        #pragma unroll
        for (int mt = 0; mt < 2; ++mt)
            #pragma unroll
            for (int r = 0; r < 4; ++r) {
                float rm = fmaxf(fmaxf(s[mt][0][r], s[mt][1][r]),
                                 fmaxf(s[mt][2][r], s[mt][3][r]));
                rm = fmaxf(rm, __shfl_xor(rm, 1, 16));
                rm = fmaxf(rm, __shfl_xor(rm, 2, 16));
                rm = fmaxf(rm, __shfl_xor(rm, 4, 16));
                rm = fmaxf(rm, __shfl_xor(rm, 8, 16));
                float m2 = fmaxf(mold[mt][r], rm * C2);
                al[mt][r]  = EXP2(mold[mt][r] - m2);
                m2n[mt][r] = m2;
            }
        float rs[2][4] = {};
        #pragma unroll
        for (int mt = 0; mt < 2; ++mt)
            #pragma unroll
            for (int nt = 0; nt < 4; ++nt)
                #pragma unroll
                for (int r = 0; r < 4; ++r) {
                    float p = EXP2(fmaf(s[mt][nt][r], C2, -m2n[mt][r]));
                    s[mt][nt][r] = p;
                    rs[mt][r] += p;
                }
        #pragma unroll
        for (int mt = 0; mt < 2; ++mt)
            #pragma unroll
            for (int r = 0; r < 4; ++r) {
                float t = rs[mt][r];
                t += __shfl_xor(t, 1, 16);
                t += __shfl_xor(t, 2, 16);
                t += __shfl_xor(t, 4, 16);
                t += __shfl_xor(t, 8, 16);
                lsum[mt][r] = lsum[mt][r]*al[mt][r] + t;
                mold[mt][r] = m2n[mt][r];
            }

        // ---- P -> LDS (this wave's private buffer; same-wave RAW, no barrier)
        #pragma unroll
        for (int mt = 0; mt < 2; ++mt)
            #pragma unroll
            for (int nt = 0; nt < 4; ++nt)
                #pragma unroll
                for (int r = 0; r < 4; ++r) {
                    union { float f; uint32_t u; } c; c.f = s[mt][nt][r];
                    Ps[(mt*16 + quad*4 + r)*PST + nt*16 + l16] =
                        (unsigned short)((c.u + 0x8000u) >> 16);
                }

        // ---- O = O*alpha + P V
        #pragma unroll
        for (int mt = 0; mt < 2; ++mt)
            #pragma unroll
            for (int dt = 0; dt < 4; ++dt)
                #pragma unroll
                for (int r = 0; r < 4; ++r)
                    o[mt][dt][r] *= al[mt][r];
        #pragma unroll
        for (int kk = 0; kk < 2; ++kk) {
            short8 ap0 = *(short8*)&Ps[(     l16)*PST + kk*32 + quad*8];
            short8 ap1 = *(short8*)&Ps[(16 + l16)*PST + kk*32 + quad*8];
            #pragma unroll
            for (int dt = 0; dt < 4; ++dt) {
                o[0][dt] = __builtin_amdgcn_mfma_f32_16x16x32_bf16(ap0, bv[kk][dt], o[0][dt], 0, 0, 0);
                o[1][dt] = __builtin_amdgcn_mfma_f32_16x16x32_bf16(ap1, bv[kk][dt], o[1][dt], 0, 0, 0);
            }
        }
    }

    // ---- normalize + store (bf16 intermediate Y)
    #pragma unroll
    for (int mt = 0; mt < 2; ++mt)
        #pragma unroll
        for (int r = 0; r < 4; ++r) {
            float inv = 1.0f / lsum[mt][r];
            int t = q0w + mt*16 + quad*4 + r;
            #pragma unroll
            for (int dt = 0; dt < 4; ++dt)
                Y[((size_t)(b*TT + t))*DD + h*64 + dt*16 + l16] = f2bf(o[mt][dt][r] * inv);
        }
}

extern "C" void kernel_launch(void* const* d_in, const int* in_sizes, int n_in,
                              void* d_out, int out_size, void* d_ws, size_t ws_size,
                              hipStream_t stream)
{
    const float* x    = (const float*)d_in[0];   // [4,2048,1024] fp32
    // d_in[1] = causal_mask (int32) — causality implemented analytically, unused
    const float* wqkv = (const float*)d_in[2];   // [1024][3072] fp32
    const float* bqkv = (const float*)d_in[3];   // [3072] fp32
    const float* wout = (const float*)d_in[4];   // [1024][1024] fp32
    const float* bout = (const float*)d_in[5];   // [1024] fp32
    float* out = (float*)d_out;                  // [4,2048,1024] fp32

    char* ws = (char*)d_ws;
    unsigned short* Xb    = (unsigned short*)ws;                    // 16 MB
    unsigned short* WqkvT = (unsigned short*)(ws + 16777216);       // 6 MB
    unsigned short* WoutT = (unsigned short*)(ws + 23068672);       // 2 MB
    unsigned short* QK    = (unsigned short*)(ws + 25165824);       // 32 MB [M][2048]
    unsigned short* VTb   = (unsigned short*)(ws + 58720256);       // 16 MB [(bh*64+d)][2048]
    unsigned short* Ybuf  = (unsigned short*)(ws + 75497472);       // 16 MB

    cvt_f32_bf16<<<(M1*KDIM/4 + 255)/256, 256, 0, stream>>>(x, Xb, M1*KDIM/4);
    transpose_f32_bf16<<<dim3(N1/32, KDIM/32), dim3(32, 8), 0, stream>>>(wqkv, WqkvT, KDIM, N1);
    transpose_f32_bf16<<<dim3(DD/32, KDIM/32), dim3(32, 8), 0, stream>>>(wout, WoutT, KDIM, DD);
    gemm_bf16_mfma<2><<<dim3(N1/128, M1/128), 256, 0, stream>>>(Xb, WqkvT, bqkv, QK, VTb, M1, N1, KDIM);
    attn_mfma<<<dim3(TT/32, BB*HH), 64, 0, stream>>>(QK, VTb, Ybuf);
    gemm_bf16_mfma<1><<<dim3(DD/128, M1/128), 256, 0, stream>>>(Ybuf, WoutT, bout, out, nullptr, M1, DD, KDIM);
}

// Round 7
// 391.708 us; speedup vs baseline: 1.4882x; 1.1602x over previous
//
#include <hip/hip_runtime.h>
#include <hip/hip_bf16.h>
#include <stdint.h>

// Problem constants
#define BB 4
#define TT 2048
#define DD 1024
#define HH 16
#define HDD 64
// derived
#define M1 (BB*TT)      // 8192 rows
#define N1 (3*DD)       // 3072
#define KDIM DD         // 1024

typedef __attribute__((ext_vector_type(8))) short short8;   // 8 bf16 MFMA operand
typedef __attribute__((ext_vector_type(4))) float f32x4;

#if __has_builtin(__builtin_amdgcn_exp2f)
#define EXP2(x) __builtin_amdgcn_exp2f(x)
#else
#define EXP2(x) exp2f(x)
#endif

// async global->LDS, 16B per lane (global_load_lds_dwordx4)
#define GLOAD_LDS16(gp, lp) \
    __builtin_amdgcn_global_load_lds( \
        (const __attribute__((address_space(1))) void*)(gp), \
        (__attribute__((address_space(3))) void*)(lp), 16, 0, 0)

__device__ __forceinline__ float bf2f(unsigned short u) {
    union { uint32_t u32; float f; } c; c.u32 = ((uint32_t)u) << 16; return c.f;
}
__device__ __forceinline__ unsigned short f2bf(float f) {
    union { float f; uint32_t u32; } c; c.f = f;
    uint32_t u = c.u32;
    return (unsigned short)((u + 0x7FFFu + ((u >> 16) & 1u)) >> 16);  // RNE
}

// ---------------- elementwise fp32 -> bf16 (x), 4 elems/thread ----------------
__global__ __launch_bounds__(256) void cvt_f32_bf16(
    const float* __restrict__ in, unsigned short* __restrict__ out, int n4)
{
    int i = blockIdx.x * 256 + threadIdx.x;
    if (i >= n4) return;
    float4 v = *(const float4*)&in[(size_t)i * 4];
    ushort4 o;
    o.x = f2bf(v.x); o.y = f2bf(v.y); o.z = f2bf(v.z); o.w = f2bf(v.w);
    *(ushort4*)&out[(size_t)i * 4] = o;
}

// ---------------- transpose+convert: in fp32 [R][C] -> out bf16 [C][R] ----------------
__global__ __launch_bounds__(256) void transpose_f32_bf16(
    const float* __restrict__ in, unsigned short* __restrict__ out,
    int R, int C)
{
    __shared__ unsigned short tile[32][33];
    int bx = blockIdx.x;
    int by = blockIdx.y;
    int x = bx*32 + threadIdx.x;
    int y0 = by*32 + threadIdx.y;
    #pragma unroll
    for (int i = 0; i < 32; i += 8)
        tile[threadIdx.y + i][threadIdx.x] = f2bf(in[(size_t)(y0 + i)*C + x]);
    __syncthreads();
    int xo = by*32 + threadIdx.x;
    int yo = bx*32 + threadIdx.y;
    #pragma unroll
    for (int i = 0; i < 32; i += 8)
        out[(size_t)(yo + i)*R + xo] = tile[threadIdx.x][threadIdx.y + i];
}

// ---------------- MFMA bf16 GEMM ----------------
// MODE 1: f32 C[M][N]
// MODE 2: QKV-split — n<2048 -> bf16 QK[M][2048]; n>=2048 -> V transposed via
//         LDS to VT[((b*16+h)*64+d)][2048]+t with fully-coalesced 16B stores.
// Staging via global_load_lds width=16 (m97 pattern).
#define TSTR 132
template <int MODE>
__global__ __launch_bounds__(256) void gemm_bf16_mfma(
    const unsigned short* __restrict__ A, const unsigned short* __restrict__ BT,
    const float* __restrict__ bias, void* __restrict__ Cout, void* __restrict__ Cout2,
    int M, int N, int K)
{
    constexpr int SHSZ = (MODE == 2) ? 128*TSTR : 128*64;
    __shared__ __align__(16) unsigned short Sh[SHSZ];
    unsigned short* As = Sh;            // 128*32 shorts
    unsigned short* Bs = Sh + 128*32;   // 128*32 shorts
    const int tid  = threadIdx.x;
    const int lane = tid & 63;
    const int wave = tid >> 6;
    const int wm = wave >> 1, wn = wave & 1;
    const int quad = lane >> 4, l16 = lane & 15;
    const int m0 = blockIdx.y * 128, n0 = blockIdx.x * 128;

    f32x4 acc[4][4] = {};

    const int nk = K >> 5;
    for (int kt = 0; kt < nk; ++kt) {
        const int k0 = kt << 5;
        __syncthreads();
        #pragma unroll
        for (int h = 0; h < 2; ++h) {
            int c = tid + h*256;
            int row = c >> 2, seg = c & 3;
            GLOAD_LDS16(&A[(size_t)(m0 + row)*K + k0 + seg*8], &As[row*32 + seg*8]);
            GLOAD_LDS16(&BT[(size_t)(n0 + row)*K + k0 + seg*8], &Bs[row*32 + seg*8]);
        }
        __syncthreads();   // compiler drains vmcnt before barrier
        short8 af[4], bf[4];
        #pragma unroll
        for (int mi = 0; mi < 4; ++mi)
            af[mi] = *(short8*)&As[(wm*64 + mi*16 + l16)*32 + quad*8];
        #pragma unroll
        for (int ni = 0; ni < 4; ++ni)
            bf[ni] = *(short8*)&Bs[(wn*64 + ni*16 + l16)*32 + quad*8];
        #pragma unroll
        for (int mi = 0; mi < 4; ++mi)
            #pragma unroll
            for (int ni = 0; ni < 4; ++ni)
                acc[mi][ni] = __builtin_amdgcn_mfma_f32_16x16x32_bf16(
                    af[mi], bf[ni], acc[mi][ni], 0, 0, 0);
    }

    if (MODE == 2 && n0 >= 2048) {
        // V third: transpose through LDS, then coalesced 16B stores to VT[d-row][t]
        __syncthreads();   // all As/Bs reads done before aliasing Sh
        #pragma unroll
        for (int ni = 0; ni < 4; ++ni) {
            int nl = wn*64 + ni*16 + l16;        // local n 0..127
            float bv = bias[n0 + nl];
            #pragma unroll
            for (int mi = 0; mi < 4; ++mi) {
                ushort4 pk;
                pk.x = f2bf(acc[mi][ni][0] + bv);
                pk.y = f2bf(acc[mi][ni][1] + bv);
                pk.z = f2bf(acc[mi][ni][2] + bv);
                pk.w = f2bf(acc[mi][ni][3] + bv);
                *(ushort4*)&Sh[nl*TSTR + wm*64 + mi*16 + quad*4] = pk;
            }
        }
        __syncthreads();
        const int bb = m0 >> 11, t0 = m0 & 2047;
        #pragma unroll
        for (int p = 0; p < 8; ++p) {
            int c = tid + p*256;
            int row = c >> 4, ch = c & 15;       // row: local n, ch: 8-short chunk of m
            int nv = n0 + row - 2048;            // 0..1023
            int hv = nv >> 6, dv = nv & 63;
            *(uint4*)&((unsigned short*)Cout2)[((size_t)((bb*16 + hv)*64 + dv))*2048 + t0 + ch*8] =
                *(uint4*)&Sh[row*TSTR + ch*8];
        }
        return;
    }

    const int cstride = (MODE == 2) ? 2048 : N;
    #pragma unroll
    for (int ni = 0; ni < 4; ++ni) {
        int n = n0 + wn*64 + ni*16 + l16;
        float bv = bias[n];
        #pragma unroll
        for (int mi = 0; mi < 4; ++mi) {
            #pragma unroll
            for (int r = 0; r < 4; ++r) {
                int m = m0 + wm*64 + mi*16 + quad*4 + r;
                float val = acc[mi][ni][r] + bv;
                if (MODE == 1)
                    ((float*)Cout)[(size_t)m*cstride + n] = val;
                else
                    ((unsigned short*)Cout)[(size_t)m*cstride + n] = f2bf(val);
            }
        }
    }
}

// ---------------- MFMA flash attention: barrier-free per-wave ----------------
// Flat grid 4096 blocks of 1 wave (64 thr). XCD-aware swizzle: with the HW's
// round-robin block->XCD dealing, xcd = i&7 pins all 64 q-tiles of one bh to
// one XCD, so its private L2 holds ONE 512 KB K/V slice (round-6 layout
// spread each bh across all 8 XCDs -> FETCH 132 MB vs ~48 ideal).
// __launch_bounds__(64, 3): 170-reg unified budget; measured use is
// 88 VGPR + 64 AGPR = 152, fits -> 3 waves/SIMD (round 6 ran ~1/SIMD).
// (64,4) = 128-reg budget SPILLS (~300 MB scratch traffic, round 5).
#define PST 72
__global__ __launch_bounds__(64, 3) void attn_mfma(
    const unsigned short* __restrict__ QK, const unsigned short* __restrict__ VT,
    unsigned short* __restrict__ Y)
{
    __shared__ __align__(16) unsigned short Ps[32*PST];

    const int lane = threadIdx.x;
    const int quad = lane >> 4, l16 = lane & 15;
    const int i = blockIdx.x;
    const int xcd = i & 7, j = i >> 3;
    const int qw = 63 - (j & 63);              // long causal rows first per XCD
    const int bh = xcd + 8*(j >> 6);
    const int b = bh >> 4, h = bh & 15;
    const int q0w = qw * 32;
    const size_t qkbase = (size_t)(b*TT) * 2048;
    const size_t vbase  = (size_t)(bh*64) * 2048;
    const int qcol = h*64, kcol = 1024 + h*64;
    const float C2 = 0.18033688011112042f;   // (1/sqrt(64)) * log2(e)

    // Q fragments straight from global (held for the whole loop)
    short8 aq[2][2];
    #pragma unroll
    for (int mt = 0; mt < 2; ++mt)
        #pragma unroll
        for (int kk = 0; kk < 2; ++kk)
            aq[mt][kk] = *(const short8*)&QK[qkbase + (size_t)(q0w + mt*16 + l16)*2048
                                            + qcol + kk*32 + quad*8];

    f32x4 o[2][4] = {};
    float mold[2][4], lsum[2][4];
    #pragma unroll
    for (int mt = 0; mt < 2; ++mt)
        #pragma unroll
        for (int r = 0; r < 4; ++r) { mold[mt][r] = -3.0e38f; lsum[mt][r] = 0.0f; }

    const int nkt = ((q0w + 31) >> 6) + 1;

    for (int kt = 0; kt < nkt; ++kt) {
        const int k0 = kt * 64;

        // ---- S = Q K^T, K frags from global (per-nt causal skip, wave-uniform)
        f32x4 s[2][4];
        #pragma unroll
        for (int nt = 0; nt < 4; ++nt) {
            if (k0 + nt*16 <= q0w + 31) {
                f32x4 z = {};
                s[0][nt] = z; s[1][nt] = z;
                #pragma unroll
                for (int kk = 0; kk < 2; ++kk) {
                    short8 bk = *(const short8*)&QK[qkbase + (size_t)(k0 + nt*16 + l16)*2048
                                                    + kcol + kk*32 + quad*8];
                    s[0][nt] = __builtin_amdgcn_mfma_f32_16x16x32_bf16(aq[0][kk], bk, s[0][nt], 0, 0, 0);
                    s[1][nt] = __builtin_amdgcn_mfma_f32_16x16x32_bf16(aq[1][kk], bk, s[1][nt], 0, 0, 0);
                }
            } else {
                #pragma unroll
                for (int r = 0; r < 4; ++r) { s[0][nt][r] = -3.0e38f; s[1][nt][r] = -3.0e38f; }
            }
        }

        // ---- issue V-frag loads now; latency hides under softmax (independent)
        short8 bv[2][4];
        #pragma unroll
        for (int kk = 0; kk < 2; ++kk)
            #pragma unroll
            for (int dt = 0; dt < 4; ++dt)
                bv[kk][dt] = *(const short8*)&VT[vbase + (size_t)(dt*16 + l16)*2048
                                                 + k0 + kk*32 + quad*8];

        // ---- element causal mask (straddling tiles only)
        if (k0 + 63 > q0w) {
            #pragma unroll
            for (int mt = 0; mt < 2; ++mt)
                #pragma unroll
                for (int nt = 0; nt < 4; ++nt)
                    #pragma unroll
                    for (int r = 0; r < 4; ++r) {
                        int kg = k0 + nt*16 + l16;
                        int qg = q0w + mt*16 + quad*4 + r;
                        if (kg > qg) s[mt][nt][r] = -3.0e38f;
                    }
        }

        // ---- online softmax (exp2 domain)
        float m2n[2][4], al[2][4];
        #pragma unroll
        for (int mt = 0; mt < 2; ++mt)
            #pragma unroll
            for (int r = 0; r < 4; ++r) {
                float rm = fmaxf(fmaxf(s[mt][0][r], s[mt][1][r]),
                                 fmaxf(s[mt][2][r], s[mt][3][r]));
                rm = fmaxf(rm, __shfl_xor(rm, 1, 16));
                rm = fmaxf(rm, __shfl_xor(rm, 2, 16));
                rm = fmaxf(rm, __shfl_xor(rm, 4, 16));
                rm = fmaxf(rm, __shfl_xor(rm, 8, 16));
                float m2 = fmaxf(mold[mt][r], rm * C2);
                al[mt][r]  = EXP2(mold[mt][r] - m2);
                m2n[mt][r] = m2;
            }
        float rs[2][4] = {};
        #pragma unroll
        for (int mt = 0; mt < 2; ++mt)
            #pragma unroll
            for (int nt = 0; nt < 4; ++nt)
                #pragma unroll
                for (int r = 0; r < 4; ++r) {
                    float p = EXP2(fmaf(s[mt][nt][r], C2, -m2n[mt][r]));
                    s[mt][nt][r] = p;
                    rs[mt][r] += p;
                }
        #pragma unroll
        for (int mt = 0; mt < 2; ++mt)
            #pragma unroll
            for (int r = 0; r < 4; ++r) {
                float t = rs[mt][r];
                t += __shfl_xor(t, 1, 16);
                t += __shfl_xor(t, 2, 16);
                t += __shfl_xor(t, 4, 16);
                t += __shfl_xor(t, 8, 16);
                lsum[mt][r] = lsum[mt][r]*al[mt][r] + t;
                mold[mt][r] = m2n[mt][r];
            }

        // ---- P -> LDS (this wave's private buffer; same-wave RAW, no barrier)
        #pragma unroll
        for (int mt = 0; mt < 2; ++mt)
            #pragma unroll
            for (int nt = 0; nt < 4; ++nt)
                #pragma unroll
                for (int r = 0; r < 4; ++r) {
                    union { float f; uint32_t u; } c; c.f = s[mt][nt][r];
                    Ps[(mt*16 + quad*4 + r)*PST + nt*16 + l16] =
                        (unsigned short)((c.u + 0x8000u) >> 16);
                }

        // ---- O = O*alpha + P V
        #pragma unroll
        for (int mt = 0; mt < 2; ++mt)
            #pragma unroll
            for (int dt = 0; dt < 4; ++dt)
                #pragma unroll
                for (int r = 0; r < 4; ++r)
                    o[mt][dt][r] *= al[mt][r];
        #pragma unroll
        for (int kk = 0; kk < 2; ++kk) {
            short8 ap0 = *(short8*)&Ps[(     l16)*PST + kk*32 + quad*8];
            short8 ap1 = *(short8*)&Ps[(16 + l16)*PST + kk*32 + quad*8];
            #pragma unroll
            for (int dt = 0; dt < 4; ++dt) {
                o[0][dt] = __builtin_amdgcn_mfma_f32_16x16x32_bf16(ap0, bv[kk][dt], o[0][dt], 0, 0, 0);
                o[1][dt] = __builtin_amdgcn_mfma_f32_16x16x32_bf16(ap1, bv[kk][dt], o[1][dt], 0, 0, 0);
            }
        }
    }

    // ---- normalize + store (bf16 intermediate Y)
    #pragma unroll
    for (int mt = 0; mt < 2; ++mt)
        #pragma unroll
        for (int r = 0; r < 4; ++r) {
            float inv = 1.0f / lsum[mt][r];
            int t = q0w + mt*16 + quad*4 + r;
            #pragma unroll
            for (int dt = 0; dt < 4; ++dt)
                Y[((size_t)(b*TT + t))*DD + h*64 + dt*16 + l16] = f2bf(o[mt][dt][r] * inv);
        }
}

extern "C" void kernel_launch(void* const* d_in, const int* in_sizes, int n_in,
                              void* d_out, int out_size, void* d_ws, size_t ws_size,
                              hipStream_t stream)
{
    const float* x    = (const float*)d_in[0];   // [4,2048,1024] fp32
    // d_in[1] = causal_mask (int32) — causality implemented analytically, unused
    const float* wqkv = (const float*)d_in[2];   // [1024][3072] fp32
    const float* bqkv = (const float*)d_in[3];   // [3072] fp32
    const float* wout = (const float*)d_in[4];   // [1024][1024] fp32
    const float* bout = (const float*)d_in[5];   // [1024] fp32
    float* out = (float*)d_out;                  // [4,2048,1024] fp32

    char* ws = (char*)d_ws;
    unsigned short* Xb    = (unsigned short*)ws;                    // 16 MB
    unsigned short* WqkvT = (unsigned short*)(ws + 16777216);       // 6 MB
    unsigned short* WoutT = (unsigned short*)(ws + 23068672);       // 2 MB
    unsigned short* QK    = (unsigned short*)(ws + 25165824);       // 32 MB [M][2048]
    unsigned short* VTb   = (unsigned short*)(ws + 58720256);       // 16 MB [(bh*64+d)][2048]
    unsigned short* Ybuf  = (unsigned short*)(ws + 75497472);       // 16 MB

    cvt_f32_bf16<<<(M1*KDIM/4 + 255)/256, 256, 0, stream>>>(x, Xb, M1*KDIM/4);
    transpose_f32_bf16<<<dim3(N1/32, KDIM/32), dim3(32, 8), 0, stream>>>(wqkv, WqkvT, KDIM, N1);
    transpose_f32_bf16<<<dim3(DD/32, KDIM/32), dim3(32, 8), 0, stream>>>(wout, WoutT, KDIM, DD);
    gemm_bf16_mfma<2><<<dim3(N1/128, M1/128), 256, 0, stream>>>(Xb, WqkvT, bqkv, QK, VTb, M1, N1, KDIM);
    attn_mfma<<<dim3(4096), 64, 0, stream>>>(QK, VTb, Ybuf);
    gemm_bf16_mfma<1><<<dim3(DD/128, M1/128), 256, 0, stream>>>(Ybuf, WoutT, bout, out, nullptr, M1, DD, KDIM);
}